// Round 1
// baseline (103.112 us; speedup 1.0000x reference)
//
#include <hip/hip_runtime.h>

#define NB 8
#define NT 1024
#define NK 8
#define NL 1024
#define NH 256
#define NE 128
#define NF 64
#define NV 23

// ---------------------------------------------------------------------------
// GEMM1: Uex[r, n] = ex[r, 0:128] @ W1[256:384, n],  r = (b*NK + k)*NL + l
// M = 65536, K = 128, N = 256.  64x64 block tile, 4x4 microtile, BK=16.
// ---------------------------------------------------------------------------
__global__ __launch_bounds__(256) void k_gemm_ex(const float* __restrict__ ex,
                                                 const float* __restrict__ W1,
                                                 float* __restrict__ Uex) {
  __shared__ float As[16][68];  // As[e][m]  (transposed A tile, +pad)
  __shared__ float Bs[16][68];  // Bs[e][n]
  const int tid = threadIdx.x;
  const int row0 = blockIdx.x * 64;
  const int col0 = blockIdx.y * 64;
  const int tm = tid & 15;         // micro-row group
  const int tn = tid >> 4;         // micro-col group
  const int lm = tid >> 2;         // A-load: row in tile (0..63)
  const int le0 = (tid & 3) << 2;  // A-load: e offset (0,4,8,12)
  const int be = tid >> 4;         // B-load: e (0..15)
  const int bn0 = (tid & 15) << 2; // B-load: n offset (0..60)

  float acc[4][4] = {};
  for (int kk = 0; kk < NE; kk += 16) {
    __syncthreads();
    float4 a4 = *(const float4*)&ex[(size_t)(row0 + lm) * NE + kk + le0];
    As[le0 + 0][lm] = a4.x;
    As[le0 + 1][lm] = a4.y;
    As[le0 + 2][lm] = a4.z;
    As[le0 + 3][lm] = a4.w;
    *(float4*)&Bs[be][bn0] =
        *(const float4*)&W1[(size_t)(NH + kk + be) * NH + col0 + bn0];
    __syncthreads();
#pragma unroll
    for (int e = 0; e < 16; ++e) {
      float4 a = *(const float4*)&As[e][tm << 2];
      float4 b = *(const float4*)&Bs[e][tn << 2];
      float av[4] = {a.x, a.y, a.z, a.w};
      float bv[4] = {b.x, b.y, b.z, b.w};
#pragma unroll
      for (int i = 0; i < 4; ++i)
#pragma unroll
        for (int j = 0; j < 4; ++j) acc[i][j] = fmaf(av[i], bv[j], acc[i][j]);
    }
  }
#pragma unroll
  for (int i = 0; i < 4; ++i) {
    float4 o = make_float4(acc[i][0], acc[i][1], acc[i][2], acc[i][3]);
    *(float4*)&Uex[(size_t)(row0 + (tm << 2) + i) * NH + col0 + (tn << 2)] = o;
  }
}

// ---------------------------------------------------------------------------
// GEMM2: Ubase[r, n] = hs[r, 0:256] @ W1[0:256, n]
//                    + col[b, c_t[r], 0:64] @ W1[384:448, n] + b1[n]
// r = b*NT + t.  M = 8192, K = 320 (gathered), N = 256.
// ---------------------------------------------------------------------------
__global__ __launch_bounds__(256) void k_base(const float* __restrict__ hs,
                                              const float* __restrict__ col,
                                              const int* __restrict__ c_t,
                                              const float* __restrict__ W1,
                                              const float* __restrict__ b1,
                                              float* __restrict__ Ubase) {
  __shared__ float As[16][68];
  __shared__ float Bs[16][68];
  __shared__ int c_sh[64];
  const int tid = threadIdx.x;
  const int row0 = blockIdx.x * 64;
  const int col0 = blockIdx.y * 64;
  const int tm = tid & 15;
  const int tn = tid >> 4;
  const int lm = tid >> 2;
  const int le0 = (tid & 3) << 2;
  const int be = tid >> 4;
  const int bn0 = (tid & 15) << 2;

  if (tid < 64) {
    int v = c_t[row0 + tid];
    c_sh[tid] = v < 0 ? 0 : v;
  }

  float4 b1v = *(const float4*)&b1[col0 + (tn << 2)];
  float acc[4][4];
#pragma unroll
  for (int i = 0; i < 4; ++i) {
    acc[i][0] = b1v.x; acc[i][1] = b1v.y; acc[i][2] = b1v.z; acc[i][3] = b1v.w;
  }

  const int r = row0 + lm;
  const int b = r >> 10;

  for (int kk = 0; kk < NH + NF; kk += 16) {
    __syncthreads();
    float4 a4;
    if (kk < NH) {
      a4 = *(const float4*)&hs[(size_t)r * NH + kk + le0];
    } else {
      a4 = *(const float4*)&col[(size_t)(b * NL + c_sh[lm]) * NF + (kk - NH) + le0];
    }
    As[le0 + 0][lm] = a4.x;
    As[le0 + 1][lm] = a4.y;
    As[le0 + 2][lm] = a4.z;
    As[le0 + 3][lm] = a4.w;
    const int rIdx = kk + be;
    const int wrow = rIdx < NH ? rIdx : rIdx + NE;  // col features live at W1 rows 384..447
    *(float4*)&Bs[be][bn0] =
        *(const float4*)&W1[(size_t)wrow * NH + col0 + bn0];
    __syncthreads();
#pragma unroll
    for (int e = 0; e < 16; ++e) {
      float4 a = *(const float4*)&As[e][tm << 2];
      float4 bb = *(const float4*)&Bs[e][tn << 2];
      float av[4] = {a.x, a.y, a.z, a.w};
      float bv[4] = {bb.x, bb.y, bb.z, bb.w};
#pragma unroll
      for (int i = 0; i < 4; ++i)
#pragma unroll
        for (int j = 0; j < 4; ++j) acc[i][j] = fmaf(av[i], bv[j], acc[i][j]);
    }
  }
#pragma unroll
  for (int i = 0; i < 4; ++i) {
    float4 o = make_float4(acc[i][0], acc[i][1], acc[i][2], acc[i][3]);
    *(float4*)&Ubase[(size_t)(row0 + (tm << 2) + i) * NH + col0 + (tn << 2)] = o;
  }
}

// ---------------------------------------------------------------------------
// Epilogue: one wave per (b,t).
//   for k: h1 = relu(Ubase[b,t] + Uex[b,k,c]); score_k = h1 . W2 + b2
//   softmax over k, zero if invalid; write lambda and p_copy (scatter by aa).
// ---------------------------------------------------------------------------
__global__ __launch_bounds__(256) void k_final(const float* __restrict__ Ubase,
                                               const float* __restrict__ Uex,
                                               const int* __restrict__ c_t,
                                               const int* __restrict__ aa_ids,
                                               const float* __restrict__ W2,
                                               const float* __restrict__ b2,
                                               float* __restrict__ p_copy,
                                               float* __restrict__ lam) {
  const int lane = threadIdx.x & 63;
  const int wv = threadIdx.x >> 6;
  const int bt = blockIdx.x * 4 + wv;
  const int b = bt >> 10;
  const int ct = c_t[bt];
  const bool valid = ct >= 0;
  const int c = valid ? ct : 0;

  const float4 ub = *(const float4*)&Ubase[(size_t)bt * NH + (lane << 2)];
  const float4 w2 = *(const float4*)&W2[lane << 2];
  const float b2v = b2[0];

  float sc[NK];
#pragma unroll
  for (int k = 0; k < NK; ++k) {
    const float4 e4 =
        *(const float4*)&Uex[(size_t)((b * NK + k) * NL + c) * NH + (lane << 2)];
    float p = fmaxf(ub.x + e4.x, 0.f) * w2.x +
              fmaxf(ub.y + e4.y, 0.f) * w2.y +
              fmaxf(ub.z + e4.z, 0.f) * w2.z +
              fmaxf(ub.w + e4.w, 0.f) * w2.w;
#pragma unroll
    for (int off = 32; off > 0; off >>= 1) p += __shfl_xor(p, off);
    sc[k] = p + b2v;
  }

  float m = sc[0];
#pragma unroll
  for (int k = 1; k < NK; ++k) m = fmaxf(m, sc[k]);
  float w[NK], s = 0.f;
#pragma unroll
  for (int k = 0; k < NK; ++k) {
    w[k] = __expf(sc[k] - m);
    s += w[k];
  }
  const float inv = valid ? (1.f / s) : 0.f;
#pragma unroll
  for (int k = 0; k < NK; ++k) w[k] *= inv;

  if (lane < NK) lam[(size_t)bt * NK + lane] = w[lane];
  if (lane < NV) {
    float p = 0.f;
#pragma unroll
    for (int k = 0; k < NK; ++k) {
      int aa = aa_ids[(size_t)(b * NK + k) * NL + c];
      p += (aa == lane) ? w[k] : 0.f;
    }
    p_copy[(size_t)bt * NV + lane] = p;
  }
}

extern "C" void kernel_launch(void* const* d_in, const int* in_sizes, int n_in,
                              void* d_out, int out_size, void* d_ws, size_t ws_size,
                              hipStream_t stream) {
  const float* hs = (const float*)d_in[0];
  const float* ex = (const float*)d_in[1];
  const float* col = (const float*)d_in[2];
  const int* ct = (const int*)d_in[3];
  const int* aa = (const int*)d_in[4];
  const float* W1 = (const float*)d_in[5];
  const float* b1 = (const float*)d_in[6];
  const float* W2 = (const float*)d_in[7];
  const float* b2 = (const float*)d_in[8];

  float* Uex = (float*)d_ws;                                   // 64 MB
  float* Ubase = Uex + (size_t)NB * NK * NL * NH;              // +8 MB
  float* p_copy = (float*)d_out;
  float* lam = p_copy + (size_t)NB * NT * NV;

  k_gemm_ex<<<dim3((NB * NK * NL) / 64, NH / 64), 256, 0, stream>>>(ex, W1, Uex);
  k_base<<<dim3((NB * NT) / 64, NH / 64), 256, 0, stream>>>(hs, col, ct, W1, b1, Ubase);
  k_final<<<(NB * NT) / 4, 256, 0, stream>>>(Ubase, Uex, ct, aa, W2, b2, p_copy, lam);
}

// Round 2
// 61.689 us; speedup vs baseline: 1.6715x; 1.6715x over previous
//
#include <hip/hip_runtime.h>

#define NB 8
#define NT 1024
#define NK 8
#define NL 1024
#define NH 256
#define NE 128
#define NF 64
#define NV 23

typedef __attribute__((ext_vector_type(8))) short bf16x8;
typedef __attribute__((ext_vector_type(4))) float f32x4;

__device__ inline unsigned short f2bf(float f) {
  unsigned u = __float_as_uint(f);
  u += 0x7fffu + ((u >> 16) & 1u);
  return (unsigned short)(u >> 16);
}
__device__ inline float bf2f(unsigned short h) {
  return __uint_as_float(((unsigned)h) << 16);
}

// ---------------------------------------------------------------------------
// Prep: W1 rows 256..383 (ex slice) -> transposed bf16, pre-swizzled LDS image.
// Image chunk (n, g) at index g*256 + (n ^ (g&7)) holds W1[256+g*8+j][n], j=0..7.
// ---------------------------------------------------------------------------
__global__ __launch_bounds__(256) void k_prep(const float* __restrict__ W1,
                                              uint4* __restrict__ img) {
  const int c = blockIdx.x * 256 + threadIdx.x;  // 4096 chunks
  const int g = c >> 8;                          // 0..15 (k-group)
  const int n = c & 255;
  unsigned short h[8];
#pragma unroll
  for (int j = 0; j < 8; ++j)
    h[j] = f2bf(W1[(size_t)(NH + g * 8 + j) * NH + n]);
  uint4 u;
  u.x = h[0] | ((unsigned)h[1] << 16);
  u.y = h[2] | ((unsigned)h[3] << 16);
  u.z = h[4] | ((unsigned)h[5] << 16);
  u.w = h[6] | ((unsigned)h[7] << 16);
  img[g * 256 + (n ^ (g & 7))] = u;
}

// ---------------------------------------------------------------------------
// GEMM1 (MFMA): Uex[r, n] = ex[r, :] @ W1[256:384, n], bf16 in/out, f32 acc.
// M = 65536, K = 128, N = 256. Block 64x256, full K in LDS, one barrier.
// ---------------------------------------------------------------------------
__global__ __launch_bounds__(256) void k_gemm_ex(const float* __restrict__ ex,
                                                 const uint4* __restrict__ W1img,
                                                 unsigned short* __restrict__ Uex) {
  extern __shared__ uint4 smem[];
  uint4* Bs = smem;         // 4096 chunks = 64 KB (W1 image)
  uint4* As = smem + 4096;  // 1024 chunks = 16 KB (ex tile)
  const int tid = threadIdx.x;
  const int lane = tid & 63;
  const int w = tid >> 6;
  const int row0 = blockIdx.x * 64;

  // Stage B: linear 64 KB copy, global_load_lds width=16.
#pragma unroll
  for (int it = 0; it < 16; ++it) {
    const int off16 = (w * 16 + it) * 64;  // in 16B chunks
    __builtin_amdgcn_global_load_lds(
        (const __attribute__((address_space(1))) void*)(W1img + off16 + lane),
        (__attribute__((address_space(3))) void*)(Bs + off16), 16, 0, 0);
  }

  // Stage A: 64 rows x 128 k, f32 -> bf16, swizzled chunk (m ^ (g&7)).
#pragma unroll
  for (int i = 0; i < 4; ++i) {
    const int c = i * 256 + tid;
    const int m = c >> 4;  // 0..63
    const int g = c & 15;  // 0..15
    const float* src = &ex[(size_t)(row0 + m) * NE + g * 8];
    const float4 f0 = *(const float4*)src;
    const float4 f1 = *(const float4*)(src + 4);
    uint4 u;
    u.x = f2bf(f0.x) | ((unsigned)f2bf(f0.y) << 16);
    u.y = f2bf(f0.z) | ((unsigned)f2bf(f0.w) << 16);
    u.z = f2bf(f1.x) | ((unsigned)f2bf(f1.y) << 16);
    u.w = f2bf(f1.z) | ((unsigned)f2bf(f1.w) << 16);
    As[g * 64 + (m ^ (g & 7))] = u;
  }
  __syncthreads();

  const int wm0 = (w >> 1) * 32;   // wave M offset (2 waves)
  const int wn0 = (w & 1) * 128;   // wave N offset (2 waves)
  const int lm = lane & 15;
  const int lg = lane >> 4;

  f32x4 acc[2][8] = {};
#pragma unroll
  for (int ks = 0; ks < 4; ++ks) {
    const int g = ks * 4 + lg;
    bf16x8 afr[2], bfr[8];
#pragma unroll
    for (int fm = 0; fm < 2; ++fm) {
      const int m = wm0 + fm * 16 + lm;
      afr[fm] = *(const bf16x8*)&As[g * 64 + (m ^ (g & 7))];
    }
#pragma unroll
    for (int fn = 0; fn < 8; ++fn) {
      const int n = wn0 + fn * 16 + lm;
      bfr[fn] = *(const bf16x8*)&Bs[g * 256 + (n ^ (g & 7))];
    }
#pragma unroll
    for (int fm = 0; fm < 2; ++fm)
#pragma unroll
      for (int fn = 0; fn < 8; ++fn)
        acc[fm][fn] = __builtin_amdgcn_mfma_f32_16x16x32_bf16(
            bfr[fn], afr[fm], acc[fm][fn], 0, 0, 0);
  }

  // D = W1frag x exfrag: reg index runs along n -> contiguous bf16x4 stores.
#pragma unroll
  for (int fm = 0; fm < 2; ++fm) {
    const int m = row0 + wm0 + fm * 16 + lm;
#pragma unroll
    for (int fn = 0; fn < 8; ++fn) {
      const int n = wn0 + fn * 16 + 4 * lg;
      const f32x4 a = acc[fm][fn];
      ushort4 o;
      o.x = f2bf(a[0]); o.y = f2bf(a[1]); o.z = f2bf(a[2]); o.w = f2bf(a[3]);
      *(ushort4*)&Uex[(size_t)m * NH + n] = o;
    }
  }
}

// ---------------------------------------------------------------------------
// GEMM2 (f32 vector, unchanged): Ubase = hs @ W1[0:256] + col_gather @ W1[384:448] + b1
// ---------------------------------------------------------------------------
__global__ __launch_bounds__(256) void k_base(const float* __restrict__ hs,
                                              const float* __restrict__ col,
                                              const int* __restrict__ c_t,
                                              const float* __restrict__ W1,
                                              const float* __restrict__ b1,
                                              float* __restrict__ Ubase) {
  __shared__ float As[16][68];
  __shared__ float Bs[16][68];
  __shared__ int c_sh[64];
  const int tid = threadIdx.x;
  const int row0 = blockIdx.x * 64;
  const int col0 = blockIdx.y * 64;
  const int tm = tid & 15;
  const int tn = tid >> 4;
  const int lm = tid >> 2;
  const int le0 = (tid & 3) << 2;
  const int be = tid >> 4;
  const int bn0 = (tid & 15) << 2;

  if (tid < 64) {
    int v = c_t[row0 + tid];
    c_sh[tid] = v < 0 ? 0 : v;
  }

  float4 b1v = *(const float4*)&b1[col0 + (tn << 2)];
  float acc[4][4];
#pragma unroll
  for (int i = 0; i < 4; ++i) {
    acc[i][0] = b1v.x; acc[i][1] = b1v.y; acc[i][2] = b1v.z; acc[i][3] = b1v.w;
  }

  const int r = row0 + lm;
  const int b = r >> 10;

  for (int kk = 0; kk < NH + NF; kk += 16) {
    __syncthreads();
    float4 a4;
    if (kk < NH) {
      a4 = *(const float4*)&hs[(size_t)r * NH + kk + le0];
    } else {
      a4 = *(const float4*)&col[(size_t)(b * NL + c_sh[lm]) * NF + (kk - NH) + le0];
    }
    As[le0 + 0][lm] = a4.x;
    As[le0 + 1][lm] = a4.y;
    As[le0 + 2][lm] = a4.z;
    As[le0 + 3][lm] = a4.w;
    const int rIdx = kk + be;
    const int wrow = rIdx < NH ? rIdx : rIdx + NE;
    *(float4*)&Bs[be][bn0] =
        *(const float4*)&W1[(size_t)wrow * NH + col0 + bn0];
    __syncthreads();
#pragma unroll
    for (int e = 0; e < 16; ++e) {
      float4 a = *(const float4*)&As[e][tm << 2];
      float4 bb = *(const float4*)&Bs[e][tn << 2];
      float av[4] = {a.x, a.y, a.z, a.w};
      float bv[4] = {bb.x, bb.y, bb.z, bb.w};
#pragma unroll
      for (int i = 0; i < 4; ++i)
#pragma unroll
        for (int j = 0; j < 4; ++j) acc[i][j] = fmaf(av[i], bv[j], acc[i][j]);
    }
  }
#pragma unroll
  for (int i = 0; i < 4; ++i) {
    float4 o = make_float4(acc[i][0], acc[i][1], acc[i][2], acc[i][3]);
    *(float4*)&Ubase[(size_t)(row0 + (tm << 2) + i) * NH + col0 + (tn << 2)] = o;
  }
}

// ---------------------------------------------------------------------------
// Epilogue: one wave per (b,t). Uex is bf16 now.
// ---------------------------------------------------------------------------
__global__ __launch_bounds__(256) void k_final(const float* __restrict__ Ubase,
                                               const unsigned short* __restrict__ Uex,
                                               const int* __restrict__ c_t,
                                               const int* __restrict__ aa_ids,
                                               const float* __restrict__ W2,
                                               const float* __restrict__ b2,
                                               float* __restrict__ p_copy,
                                               float* __restrict__ lam) {
  const int lane = threadIdx.x & 63;
  const int wv = threadIdx.x >> 6;
  const int bt = blockIdx.x * 4 + wv;
  const int b = bt >> 10;
  const int ct = c_t[bt];
  const bool valid = ct >= 0;
  const int c = valid ? ct : 0;

  const float4 ub = *(const float4*)&Ubase[(size_t)bt * NH + (lane << 2)];
  const float4 w2 = *(const float4*)&W2[lane << 2];
  const float b2v = b2[0];

  float sc[NK];
#pragma unroll
  for (int k = 0; k < NK; ++k) {
    const ushort4 e4 =
        *(const ushort4*)&Uex[(size_t)((b * NK + k) * NL + c) * NH + (lane << 2)];
    float p = fmaxf(ub.x + bf2f(e4.x), 0.f) * w2.x +
              fmaxf(ub.y + bf2f(e4.y), 0.f) * w2.y +
              fmaxf(ub.z + bf2f(e4.z), 0.f) * w2.z +
              fmaxf(ub.w + bf2f(e4.w), 0.f) * w2.w;
#pragma unroll
    for (int off = 32; off > 0; off >>= 1) p += __shfl_xor(p, off);
    sc[k] = p + b2v;
  }

  float m = sc[0];
#pragma unroll
  for (int k = 1; k < NK; ++k) m = fmaxf(m, sc[k]);
  float w[NK], s = 0.f;
#pragma unroll
  for (int k = 0; k < NK; ++k) {
    w[k] = __expf(sc[k] - m);
    s += w[k];
  }
  const float inv = valid ? (1.f / s) : 0.f;
#pragma unroll
  for (int k = 0; k < NK; ++k) w[k] *= inv;

  if (lane < NK) lam[(size_t)bt * NK + lane] = w[lane];
  if (lane < NV) {
    float p = 0.f;
#pragma unroll
    for (int k = 0; k < NK; ++k) {
      int aa = aa_ids[(size_t)(b * NK + k) * NL + c];
      p += (aa == lane) ? w[k] : 0.f;
    }
    p_copy[(size_t)bt * NV + lane] = p;
  }
}

extern "C" void kernel_launch(void* const* d_in, const int* in_sizes, int n_in,
                              void* d_out, int out_size, void* d_ws, size_t ws_size,
                              hipStream_t stream) {
  const float* hs = (const float*)d_in[0];
  const float* ex = (const float*)d_in[1];
  const float* col = (const float*)d_in[2];
  const int* ct = (const int*)d_in[3];
  const int* aa = (const int*)d_in[4];
  const float* W1 = (const float*)d_in[5];
  const float* b1 = (const float*)d_in[6];
  const float* W2 = (const float*)d_in[7];
  const float* b2 = (const float*)d_in[8];

  unsigned short* Uex = (unsigned short*)d_ws;                          // 33.5 MB bf16
  float* Ubase = (float*)((char*)d_ws + (size_t)NB * NK * NL * NH * 2); // 8 MB
  uint4* W1img = (uint4*)((char*)Ubase + (size_t)NB * NT * NH * 4);     // 64 KB

  float* p_copy = (float*)d_out;
  float* lam = p_copy + (size_t)NB * NT * NV;

  k_prep<<<16, 256, 0, stream>>>(W1, W1img);
  k_gemm_ex<<<(NB * NK * NL) / 64, 256, 81920, stream>>>(ex, W1img, Uex);
  k_base<<<dim3((NB * NT) / 64, NH / 64), 256, 0, stream>>>(hs, col, ct, W1, b1, Ubase);
  k_final<<<(NB * NT) / 4, 256, 0, stream>>>(Ubase, Uex, ct, aa, W2, b2, p_copy, lam);
}

// Round 3
// 36.777 us; speedup vs baseline: 2.8037x; 1.6774x over previous
//
#include <hip/hip_runtime.h>

#define NB 8
#define NT 1024
#define NK 8
#define NL 1024
#define NH 256
#define NE 128
#define NF 64
#define NV 23

typedef __attribute__((ext_vector_type(8))) short bf16x8;
typedef __attribute__((ext_vector_type(4))) float f32x4;

__device__ inline unsigned short f2bf(float f) {
  unsigned u = __float_as_uint(f);
  u += 0x7fffu + ((u >> 16) & 1u);
  return (unsigned short)(u >> 16);
}

__device__ inline uint4 pack8(const float4 f0, const float4 f1) {
  uint4 u;
  u.x = f2bf(f0.x) | ((unsigned)f2bf(f0.y) << 16);
  u.y = f2bf(f0.z) | ((unsigned)f2bf(f0.w) << 16);
  u.z = f2bf(f1.x) | ((unsigned)f2bf(f1.y) << 16);
  u.w = f2bf(f1.z) | ((unsigned)f2bf(f1.w) << 16);
  return u;
}

// ---------------------------------------------------------------------------
// Prep: build two pre-swizzled bf16 images of W1 slices (chunk = 8 k x 1 n).
//  imgEx (4096 chunks): g in [0,16)  -> W1 rows 256+g*8..+7   (ex slice)
//  imgB (10240 chunks): g in [0,32)  -> W1 rows g*8..+7       (hs slice)
//                       g in [32,40) -> W1 rows 384+(g-32)*8..+7 (col slice)
//  chunk address: g*256 + (n ^ (g&7))
// ---------------------------------------------------------------------------
__global__ __launch_bounds__(256) void k_prep(const float* __restrict__ W1,
                                              uint4* __restrict__ imgEx,
                                              uint4* __restrict__ imgB) {
  const int c = blockIdx.x * 256 + threadIdx.x;  // 14336 total
  int g, n, wrow0;
  uint4* dst;
  if (c < 4096) {
    g = c >> 8; n = c & 255;
    wrow0 = NH + g * 8;
    dst = &imgEx[g * 256 + (n ^ (g & 7))];
  } else {
    const int c2 = c - 4096;
    g = c2 >> 8; n = c2 & 255;
    wrow0 = (g < 32) ? g * 8 : 384 + (g - 32) * 8;
    dst = &imgB[g * 256 + (n ^ (g & 7))];
  }
  unsigned short h[8];
#pragma unroll
  for (int j = 0; j < 8; ++j) h[j] = f2bf(W1[(size_t)(wrow0 + j) * NH + n]);
  uint4 u;
  u.x = h[0] | ((unsigned)h[1] << 16);
  u.y = h[2] | ((unsigned)h[3] << 16);
  u.z = h[4] | ((unsigned)h[5] << 16);
  u.w = h[6] | ((unsigned)h[7] << 16);
  *dst = u;
}

// ---------------------------------------------------------------------------
// k_base (MFMA): Ubase[r,n] = hs[r,:]@W1[0:256,n] + col[b,c_r,:]@W1[384:448,n] + b1
// M=8192, K=320, N=256. Block 64 x 128 (grid 128 x 2), BK=64, 5 K-steps.
// A fragments direct-to-register (f32->bf16), B from pre-swizzled image.
// ---------------------------------------------------------------------------
__global__ __launch_bounds__(256) void k_base(const float* __restrict__ hs,
                                              const float* __restrict__ col,
                                              const int* __restrict__ c_t,
                                              const uint4* __restrict__ imgB,
                                              const float* __restrict__ b1,
                                              float* __restrict__ Ubase) {
  __shared__ uint4 Bs[1024];  // 8 gs x 128 n chunks = 16 KB
  const int tid = threadIdx.x;
  const int lane = tid & 63;
  const int w = tid >> 6;
  const int row0 = blockIdx.x * 64;
  const int col0 = blockIdx.y * 128;
  const int lm = lane & 15;
  const int lg = lane >> 4;
  const int b = row0 >> 10;
  const int myrow = row0 + w * 16 + lm;

  const int ctv = c_t[myrow];
  const int myc = ctv < 0 ? 0 : ctv;

  f32x4 acc[8];
#pragma unroll
  for (int fn = 0; fn < 8; ++fn) {
    const float4 bv = *(const float4*)&b1[col0 + fn * 16 + lg * 4];
    acc[fn][0] = bv.x; acc[fn][1] = bv.y; acc[fn][2] = bv.z; acc[fn][3] = bv.w;
  }

  for (int kb = 0; kb < 5; ++kb) {
    if (kb) __syncthreads();
    // stage B slab: 1024 chunks, linear per 64-lane group
#pragma unroll
    for (int it = 0; it < 4; ++it) {
      const int off = (w * 4 + it) * 64;       // local chunk offset, gs = off>>7
      const int gs = off >> 7;
      const int nl = off & 127;
      __builtin_amdgcn_global_load_lds(
          (const __attribute__((address_space(1))) void*)(
              imgB + (size_t)(kb * 8 + gs) * 256 + col0 + nl + lane),
          (__attribute__((address_space(3))) void*)(Bs + off), 16, 0, 0);
    }
    __syncthreads();
#pragma unroll
    for (int ks = 0; ks < 2; ++ks) {
      const int gs = ks * 4 + lg;
      const int gk = kb * 8 + gs;
      const float* asrc = (gk < 32)
          ? &hs[(size_t)myrow * NH + gk * 8]
          : &col[((size_t)b * NL + myc) * NF + (gk - 32) * 8];
      const float4 f0 = *(const float4*)asrc;
      const float4 f1 = *(const float4*)(asrc + 4);
      union { uint4 u; bf16x8 v; } A;
      A.u = pack8(f0, f1);
#pragma unroll
      for (int fn = 0; fn < 8; ++fn) {
        const bf16x8 bfr =
            *(const bf16x8*)&Bs[gs * 128 + ((fn * 16 + lm) ^ (gs & 7))];
        acc[fn] = __builtin_amdgcn_mfma_f32_16x16x32_bf16(bfr, A.v, acc[fn], 0, 0, 0);
      }
    }
  }

  const size_t orow = (size_t)myrow * NH + col0;
#pragma unroll
  for (int fn = 0; fn < 8; ++fn) {
    *(float4*)&Ubase[orow + fn * 16 + lg * 4] =
        make_float4(acc[fn][0], acc[fn][1], acc[fn][2], acc[fn][3]);
  }
}

// ---------------------------------------------------------------------------
// k_fused: per block = 8 t (one b) x 8 k = 64 gathered ex rows.
//   MFMA: D[64 x 256] = ex_gather @ W1ex  (K=128, full K in LDS, one barrier)
//   Epilogue in-register: +Ubase, relu, .W2, wave-reduce, 8-lane softmax,
//   histogram into 23 bins. No Uex intermediate.
// Wave w owns rows w*16..w*16+15 (= t {w*2, w*2+1} x k 0..7), full N=256.
// ---------------------------------------------------------------------------
__global__ __launch_bounds__(256) void k_fused(const float* __restrict__ ex,
                                               const uint4* __restrict__ imgEx,
                                               const float* __restrict__ Ubase,
                                               const int* __restrict__ c_t,
                                               const int* __restrict__ aa_ids,
                                               const float* __restrict__ W2,
                                               const float* __restrict__ b2,
                                               float* __restrict__ p_copy,
                                               float* __restrict__ lam) {
  extern __shared__ uint4 smem[];
  uint4* Bs = smem;         // 4096 chunks = 64 KB
  uint4* As = smem + 4096;  // 1024 chunks = 16 KB
  const int tid = threadIdx.x;
  const int lane = tid & 63;
  const int w = tid >> 6;
  const int b = blockIdx.x >> 7;
  const int t0 = (blockIdx.x & 127) * 8;

  // stage B: full W1ex image, linear 64 KB
#pragma unroll
  for (int it = 0; it < 16; ++it) {
    const int off = (w * 16 + it) * 64;
    __builtin_amdgcn_global_load_lds(
        (const __attribute__((address_space(1))) void*)(imgEx + off + lane),
        (__attribute__((address_space(3))) void*)(Bs + off), 16, 0, 0);
  }

  // stage A: 64 gathered rows x 128 k, f32->bf16, swizzled
#pragma unroll
  for (int i = 0; i < 4; ++i) {
    const int cc = i * 256 + tid;       // 0..1023
    const int m = cc >> 4;              // row 0..63  (= tt*8 + k)
    const int g = cc & 15;              // k-chunk
    const int tt = m >> 3;
    const int k = m & 7;
    const int cv = c_t[b * NT + t0 + tt];
    const int c = cv < 0 ? 0 : cv;
    const float* src = &ex[(((size_t)b * NK + k) * NL + c) * NE + g * 8];
    const float4 f0 = *(const float4*)src;
    const float4 f1 = *(const float4*)(src + 4);
    As[g * 64 + (m ^ (g & 7))] = pack8(f0, f1);
  }
  __syncthreads();

  const int lm = lane & 15;
  const int lg = lane >> 4;

  f32x4 acc[16] = {};
#pragma unroll
  for (int ks = 0; ks < 4; ++ks) {
    const int g = ks * 4 + lg;
    const bf16x8 afr = *(const bf16x8*)&As[g * 64 + ((w * 16 + lm) ^ (g & 7))];
#pragma unroll
    for (int fn = 0; fn < 16; ++fn) {
      const bf16x8 bfr = *(const bf16x8*)&Bs[g * 256 + ((fn * 16 + lm) ^ (g & 7))];
      acc[fn] = __builtin_amdgcn_mfma_f32_16x16x32_bf16(bfr, afr, acc[fn], 0, 0, 0);
    }
  }

  // ---- epilogue (all in-register) ----
  // lane's output row: m = w*16+lm -> t = t0 + w*2 + (lm>>3), k = lm&7
  const int t = t0 + w * 2 + (lm >> 3);
  const int ctv = c_t[b * NT + t];
  const bool valid = ctv >= 0;
  const int c = valid ? ctv : 0;
  const size_t ubrow = ((size_t)b * NT + t) * NH;
  const float b2v = b2[0];

  float p = 0.f;
#pragma unroll
  for (int fn = 0; fn < 16; ++fn) {
    const int n0 = fn * 16 + lg * 4;
    const float4 ub = *(const float4*)&Ubase[ubrow + n0];
    const float4 w2v = *(const float4*)&W2[n0];
    p += fmaxf(acc[fn][0] + ub.x, 0.f) * w2v.x +
         fmaxf(acc[fn][1] + ub.y, 0.f) * w2v.y +
         fmaxf(acc[fn][2] + ub.z, 0.f) * w2v.z +
         fmaxf(acc[fn][3] + ub.w, 0.f) * w2v.w;
  }
  // reduce across the 4 lg groups (lanes sharing lm)
  p += __shfl_xor(p, 16);
  p += __shfl_xor(p, 32);
  const float score = p + b2v;

  // softmax over the 8 k (lanes grouped by lm&7 within each 8-lane group)
  float mx = score;
  mx = fmaxf(mx, __shfl_xor(mx, 1));
  mx = fmaxf(mx, __shfl_xor(mx, 2));
  mx = fmaxf(mx, __shfl_xor(mx, 4));
  const float e = __expf(score - mx);
  float s = e;
  s += __shfl_xor(s, 1);
  s += __shfl_xor(s, 2);
  s += __shfl_xor(s, 4);
  const float wgt = valid ? (e / s) : 0.f;

  // lambda: lanes 0..15 of each wave write 16 contiguous floats (2 t-rows)
  if (lg == 0) lam[((size_t)b * NT + t0 + w * 2) * NK + lm] = wgt;

  // aa ids (lanes 0..15 hold their row's id)
  int aav = 0;
  if (lg == 0) aav = aa_ids[((size_t)b * NK + (lm & 7)) * NL + c];

  // p_copy: lanes 0..22 serve bins of t (w*2), lanes 32..54 serve t (w*2+1)
  const int bin = lane & 31;
  const int half = lane >> 5;
  const int src0 = half * 8;
  float pc = 0.f;
#pragma unroll
  for (int k = 0; k < 8; ++k) {
    const int a = __shfl(aav, src0 + k);
    const float ww = __shfl(wgt, src0 + k);
    pc += (a == bin) ? ww : 0.f;
  }
  if (bin < NV)
    p_copy[((size_t)b * NT + t0 + w * 2 + half) * NV + bin] = pc;
}

extern "C" void kernel_launch(void* const* d_in, const int* in_sizes, int n_in,
                              void* d_out, int out_size, void* d_ws, size_t ws_size,
                              hipStream_t stream) {
  const float* hs = (const float*)d_in[0];
  const float* ex = (const float*)d_in[1];
  const float* col = (const float*)d_in[2];
  const int* ct = (const int*)d_in[3];
  const int* aa = (const int*)d_in[4];
  const float* W1 = (const float*)d_in[5];
  const float* b1 = (const float*)d_in[6];
  const float* W2 = (const float*)d_in[7];
  const float* b2 = (const float*)d_in[8];

  float* Ubase = (float*)d_ws;                                       // 8 MB f32
  uint4* imgEx = (uint4*)((char*)d_ws + (size_t)NB * NT * NH * 4);   // 64 KB
  uint4* imgB = imgEx + 4096;                                        // 160 KB

  float* p_copy = (float*)d_out;
  float* lam = p_copy + (size_t)NB * NT * NV;

  k_prep<<<56, 256, 0, stream>>>(W1, imgEx, imgB);
  k_base<<<dim3(128, 2), 256, 0, stream>>>(hs, col, ct, imgB, b1, Ubase);
  k_fused<<<NB * NT / 8, 256, 81920, stream>>>(ex, imgEx, Ubase, ct, aa, W2, b2,
                                               p_copy, lam);
}

// Round 4
// 33.599 us; speedup vs baseline: 3.0689x; 1.0946x over previous
//
#include <hip/hip_runtime.h>

#define NB 8
#define NT 1024
#define NK 8
#define NL 1024
#define NH 256
#define NE 128
#define NF 64
#define NV 23

typedef __attribute__((ext_vector_type(8))) short bf16x8;
typedef __attribute__((ext_vector_type(4))) float f32x4;

__device__ inline unsigned short f2bf(float f) {
  unsigned u = __float_as_uint(f);
  u += 0x7fffu + ((u >> 16) & 1u);
  return (unsigned short)(u >> 16);
}

__device__ inline uint4 pack8(const float4 f0, const float4 f1) {
  uint4 u;
  u.x = f2bf(f0.x) | ((unsigned)f2bf(f0.y) << 16);
  u.y = f2bf(f0.z) | ((unsigned)f2bf(f0.w) << 16);
  u.z = f2bf(f1.x) | ((unsigned)f2bf(f1.y) << 16);
  u.w = f2bf(f1.z) | ((unsigned)f2bf(f1.w) << 16);
  return u;
}

// ---------------------------------------------------------------------------
// Prep: two pre-swizzled bf16 images of W1 slices (chunk = 8 k x 1 n, 16 B).
//  imgEx (4096 chunks): g in [0,16)  -> W1 rows 256+g*8..+7   (ex slice)
//  imgB (10240 chunks): g in [0,32)  -> W1 rows g*8..+7       (hs slice)
//                       g in [32,40) -> W1 rows 384+(g-32)*8  (col slice)
//  chunk address: g*256 + (n ^ (g&7))
// ---------------------------------------------------------------------------
__global__ __launch_bounds__(256) void k_prep(const float* __restrict__ W1,
                                              uint4* __restrict__ imgEx,
                                              uint4* __restrict__ imgB) {
  const int c = blockIdx.x * 256 + threadIdx.x;  // 14336 total
  int g, n, wrow0;
  uint4* dst;
  if (c < 4096) {
    g = c >> 8; n = c & 255;
    wrow0 = NH + g * 8;
    dst = &imgEx[g * 256 + (n ^ (g & 7))];
  } else {
    const int c2 = c - 4096;
    g = c2 >> 8; n = c2 & 255;
    wrow0 = (g < 32) ? g * 8 : 384 + (g - 32) * 8;
    dst = &imgB[g * 256 + (n ^ (g & 7))];
  }
  unsigned short h[8];
#pragma unroll
  for (int j = 0; j < 8; ++j) h[j] = f2bf(W1[(size_t)(wrow0 + j) * NH + n]);
  uint4 u;
  u.x = h[0] | ((unsigned)h[1] << 16);
  u.y = h[2] | ((unsigned)h[3] << 16);
  u.z = h[4] | ((unsigned)h[5] << 16);
  u.w = h[6] | ((unsigned)h[7] << 16);
  *dst = u;
}

// ---------------------------------------------------------------------------
// Mega kernel: block = (b, 16 t rows), 8 waves.
//   phase 1: async-stage W1ex image (64 KB) to LDS
//   phase 2: reg-stage 128 gathered ex rows -> swizzled LDS (32 KB)
//   phase 3: base part U[16 t][256] = hs@W1hs + col@W1col + b1, M=16 fragment,
//            B-frags from global imgB, A from global hs/col -> result to LDS
//   barrier
//   phase 4: ex MFMA 128x256x128 (wave w owns rows w*16..+15, full N)
//   phase 5: in-register epilogue: relu(ex+base).W2, reduce, softmax over k,
//            lambda + p_copy histogram stores. No intermediates in HBM.
// ---------------------------------------------------------------------------
__global__ __launch_bounds__(512, 2) void k_mega(
    const float* __restrict__ hs, const float* __restrict__ ex,
    const float* __restrict__ col, const int* __restrict__ c_t,
    const int* __restrict__ aa_ids, const uint4* __restrict__ imgEx,
    const uint4* __restrict__ imgB, const float* __restrict__ b1,
    const float* __restrict__ W2, const float* __restrict__ b2,
    float* __restrict__ p_copy, float* __restrict__ lam) {
  extern __shared__ uint4 smem[];
  uint4* Bs = smem;                    // 4096 chunks = 64 KB
  uint4* As = smem + 4096;             // 2048 chunks = 32 KB
  float* Ub = (float*)(smem + 6144);   // [16][260] f32 = 16.6 KB (padded)

  const int tid = threadIdx.x;
  const int lane = tid & 63;
  const int w = tid >> 6;      // 0..7
  const int lm = lane & 15;
  const int lg = lane >> 4;
  const int b = blockIdx.x >> 6;
  const int t0 = (blockIdx.x & 63) * 16;

  // ---- phase 1: async B stage (64 KB linear) ----
#pragma unroll
  for (int it = 0; it < 8; ++it) {
    const int off = (w * 8 + it) * 64;
    __builtin_amdgcn_global_load_lds(
        (const __attribute__((address_space(1))) void*)(imgEx + off + lane),
        (__attribute__((address_space(3))) void*)(Bs + off), 16, 0, 0);
  }

  // ---- phase 2: stage 128 gathered ex rows (f32->bf16, swizzled) ----
#pragma unroll
  for (int i = 0; i < 4; ++i) {
    const int cc = i * 512 + tid;  // 0..2047
    const int m = cc >> 4;         // row 0..127 (= tt*8 + k)
    const int g = cc & 15;         // k-chunk
    const int tt = m >> 3;
    const int k = m & 7;
    const int cv = c_t[b * NT + t0 + tt];
    const int c = cv < 0 ? 0 : cv;
    const float* src = &ex[(((size_t)b * NK + k) * NL + c) * NE + g * 8];
    const float4 f0 = *(const float4*)src;
    const float4 f1 = *(const float4*)(src + 4);
    As[g * 128 + (m ^ (g & 7))] = pack8(f0, f1);
  }

  // ---- phase 3: base part, M=16, global operands ----
  {
    const int myt = t0 + lm;
    const int ctv = c_t[b * NT + myt];
    const int myc = ctv < 0 ? 0 : ctv;
    f32x4 accB[2];
#pragma unroll
    for (int f = 0; f < 2; ++f) {
      const float4 bv = *(const float4*)&b1[(w * 2 + f) * 16 + lg * 4];
      accB[f][0] = bv.x; accB[f][1] = bv.y; accB[f][2] = bv.z; accB[f][3] = bv.w;
    }
#pragma unroll
    for (int ks = 0; ks < 10; ++ks) {
      const int gk = ks * 4 + lg;  // 0..39
      const float* asrc = (gk < 32)
          ? &hs[((size_t)b * NT + myt) * NH + gk * 8]
          : &col[((size_t)b * NL + myc) * NF + (gk - 32) * 8];
      const float4 f0 = *(const float4*)asrc;
      const float4 f1 = *(const float4*)(asrc + 4);
      union { uint4 u; bf16x8 v; } A;
      A.u = pack8(f0, f1);
#pragma unroll
      for (int f = 0; f < 2; ++f) {
        const int n = (w * 2 + f) * 16 + lm;
        union { uint4 u; bf16x8 v; } B2;
        B2.u = imgB[(size_t)gk * 256 + (n ^ (gk & 7))];
        accB[f] = __builtin_amdgcn_mfma_f32_16x16x32_bf16(B2.v, A.v, accB[f], 0, 0, 0);
      }
    }
    // deposit base rows to LDS (padded stride 260 kills bank conflicts)
#pragma unroll
    for (int f = 0; f < 2; ++f) {
      *(float4*)&Ub[lm * 260 + (w * 2 + f) * 16 + lg * 4] =
          make_float4(accB[f][0], accB[f][1], accB[f][2], accB[f][3]);
    }
  }

  __syncthreads();

  // ---- phase 4: ex MFMA, wave w owns rows w*16..w*16+15, full N=256 ----
  f32x4 acc[16] = {};
#pragma unroll
  for (int ks = 0; ks < 4; ++ks) {
    const int g = ks * 4 + lg;
    const bf16x8 afr = *(const bf16x8*)&As[g * 128 + ((w * 16 + lm) ^ (g & 7))];
#pragma unroll
    for (int fn = 0; fn < 16; ++fn) {
      const bf16x8 bfr = *(const bf16x8*)&Bs[g * 256 + ((fn * 16 + lm) ^ (g & 7))];
      acc[fn] = __builtin_amdgcn_mfma_f32_16x16x32_bf16(bfr, afr, acc[fn], 0, 0, 0);
    }
  }

  // ---- phase 5: epilogue ----
  // lane's output row m = w*16+lm -> t_local = w*2 + (lm>>3), k = lm&7
  const int t_local = w * 2 + (lm >> 3);
  const int t = t0 + t_local;
  const int ctv = c_t[b * NT + t];
  const bool valid = ctv >= 0;
  const int c = valid ? ctv : 0;
  const float b2v = b2[0];

  float p = 0.f;
#pragma unroll
  for (int fn = 0; fn < 16; ++fn) {
    const int n0 = fn * 16 + lg * 4;
    const float4 ub = *(const float4*)&Ub[t_local * 260 + n0];
    const float4 w2v = *(const float4*)&W2[n0];
    p += fmaxf(acc[fn][0] + ub.x, 0.f) * w2v.x +
         fmaxf(acc[fn][1] + ub.y, 0.f) * w2v.y +
         fmaxf(acc[fn][2] + ub.z, 0.f) * w2v.z +
         fmaxf(acc[fn][3] + ub.w, 0.f) * w2v.w;
  }
  p += __shfl_xor(p, 16);
  p += __shfl_xor(p, 32);
  const float score = p + b2v;

  float mx = score;
  mx = fmaxf(mx, __shfl_xor(mx, 1));
  mx = fmaxf(mx, __shfl_xor(mx, 2));
  mx = fmaxf(mx, __shfl_xor(mx, 4));
  const float e = __expf(score - mx);
  float s = e;
  s += __shfl_xor(s, 1);
  s += __shfl_xor(s, 2);
  s += __shfl_xor(s, 4);
  const float wgt = valid ? (e / s) : 0.f;

  // lambda: lg==0 lanes cover 2 t rows x 8 k = 16 consecutive floats
  if (lg == 0) lam[((size_t)b * NT + t0 + w * 2) * NK + lm] = wgt;

  int aav = 0;
  if (lg == 0) aav = aa_ids[((size_t)b * NK + (lm & 7)) * NL + c];

  const int bin = lane & 31;
  const int half = lane >> 5;
  const int src0 = half * 8;
  float pc = 0.f;
#pragma unroll
  for (int k = 0; k < 8; ++k) {
    const int a = __shfl(aav, src0 + k);
    const float ww = __shfl(wgt, src0 + k);
    pc += (a == bin) ? ww : 0.f;
  }
  if (bin < NV)
    p_copy[((size_t)b * NT + t0 + w * 2 + half) * NV + bin] = pc;
}

extern "C" void kernel_launch(void* const* d_in, const int* in_sizes, int n_in,
                              void* d_out, int out_size, void* d_ws, size_t ws_size,
                              hipStream_t stream) {
  const float* hs = (const float*)d_in[0];
  const float* ex = (const float*)d_in[1];
  const float* col = (const float*)d_in[2];
  const int* ct = (const int*)d_in[3];
  const int* aa = (const int*)d_in[4];
  const float* W1 = (const float*)d_in[5];
  const float* b1 = (const float*)d_in[6];
  const float* W2 = (const float*)d_in[7];
  const float* b2 = (const float*)d_in[8];

  uint4* imgEx = (uint4*)d_ws;        // 64 KB
  uint4* imgB = imgEx + 4096;         // 160 KB

  float* p_copy = (float*)d_out;
  float* lam = p_copy + (size_t)NB * NT * NV;

  const size_t lds_bytes = (4096 + 2048) * sizeof(uint4) + 16 * 260 * sizeof(float);

  k_prep<<<56, 256, 0, stream>>>(W1, imgEx, imgB);
  k_mega<<<NB * NT / 16, 512, lds_bytes, stream>>>(hs, ex, col, ct, aa, imgEx,
                                                   imgB, b1, W2, b2, p_copy, lam);
}